// Round 1
// baseline (45.867 us; speedup 1.0000x reference)
//
#include <hip/hip_runtime.h>
#include <math.h>

#define NEXP 16

__global__ __launch_bounds__(256) void sparsemixer_kernel(
    const float* __restrict__ logits, float* __restrict__ out, int n_tok) {
    int t = blockIdx.x * blockDim.x + threadIdx.x;
    if (t >= n_tok) return;

    // Load the 16-logit row into registers (4 x float4 = 64B, one cache line per lane).
    float x[NEXP];
    const float4* row = reinterpret_cast<const float4*>(logits + (size_t)t * NEXP);
#pragma unroll
    for (int q = 0; q < 4; ++q) {
        float4 v = row[q];
        x[4 * q + 0] = v.x;
        x[4 * q + 1] = v.y;
        x[4 * q + 2] = v.z;
        x[4 * q + 3] = v.w;
    }

    // ---- iteration 0: argmax (first-index-of-max -> strict >) ----
    float m0 = x[0];
    int mi0 = 0;
#pragma unroll
    for (int j = 1; j < NEXP; ++j) {
        if (x[j] > m0) { m0 = x[j]; mi0 = j; }
    }
    // masked softmax denominator; max itself always kept (rel==0)
    float sum0 = 0.f;
#pragma unroll
    for (int j = 0; j < NEXP; ++j) {
        float rel = (m0 - x[j]) / fmaxf(fabsf(x[j]), m0);
        bool masked = (rel > 0.02f);          // NaN compares false -> kept, matches JAX
        sum0 += masked ? 0.f : __expf(x[j] - m0);
    }
    float v0 = 1.f / sum0;

    // ---- iteration 1: knock out mi0, repeat ----
    float m1 = -INFINITY;
    int mi1 = 0;
#pragma unroll
    for (int j = 0; j < NEXP; ++j) {
        if (j == mi0) continue;
        if (x[j] > m1) { m1 = x[j]; mi1 = j; }
    }
    float sum1 = 0.f;
#pragma unroll
    for (int j = 0; j < NEXP; ++j) {
        if (j == mi0) continue;
        float rel = (m1 - x[j]) / fmaxf(fabsf(x[j]), m1);
        bool masked = (rel > 0.02f);
        sum1 += masked ? 0.f : __expf(x[j] - m1);
    }
    float v1 = 1.f / sum1;

    // ---- outputs: [N,2] indices (as float), then [N,2] values ----
    float2* oidx = reinterpret_cast<float2*>(out);
    float2* oval = reinterpret_cast<float2*>(out) + n_tok;
    oidx[t] = make_float2((float)mi0, (float)mi1);
    oval[t] = make_float2(v0, v1);
}

extern "C" void kernel_launch(void* const* d_in, const int* in_sizes, int n_in,
                              void* d_out, int out_size, void* d_ws, size_t ws_size,
                              hipStream_t stream) {
    const float* logits = (const float*)d_in[0];
    float* out = (float*)d_out;
    int n_tok = in_sizes[0] / NEXP;
    int block = 256;
    int grid = (n_tok + block - 1) / block;
    sparsemixer_kernel<<<grid, block, 0, stream>>>(logits, out, n_tok);
}

// Round 2
// 31.116 us; speedup vs baseline: 1.4741x; 1.4741x over previous
//
#include <hip/hip_runtime.h>
#include <math.h>

#define NEXP 16

__global__ __launch_bounds__(256) void sparsemixer_kernel(
    const float* __restrict__ logits, float* __restrict__ out, int n_tok) {
    int t = blockIdx.x * blockDim.x + threadIdx.x;
    if (t >= n_tok) return;

    // Load the 16-logit row into registers (4 x float4 = 64B per lane, coalesced).
    float x[NEXP];
    const float4* row = reinterpret_cast<const float4*>(logits + (size_t)t * NEXP);
#pragma unroll
    for (int q = 0; q < 4; ++q) {
        float4 v = row[q];
        x[4 * q + 0] = v.x;
        x[4 * q + 1] = v.y;
        x[4 * q + 2] = v.z;
        x[4 * q + 3] = v.w;
    }

    // ---- iteration 0: argmax (first-index-of-max -> strict >) ----
    float m0 = x[0];
    int mi0 = 0;
#pragma unroll
    for (int j = 1; j < NEXP; ++j) {
        if (x[j] > m0) { m0 = x[j]; mi0 = j; }
    }
    // masked softmax denominator; divide-free mask test:
    //   (m-x)/max(|x|,m) > 0.02  <=>  (m-x) > 0.02*max(|x|,m)   [den >= 0 always;
    //   den==0 => ref rel=NaN => kept; here 0>0 false => kept. identical]
    float sum0 = 0.f;
#pragma unroll
    for (int j = 0; j < NEXP; ++j) {
        float den = fmaxf(fabsf(x[j]), m0);
        bool masked = (m0 - x[j]) > 0.02f * den;
        sum0 += masked ? 0.f : __expf(x[j] - m0);
    }
    float v0 = __builtin_amdgcn_rcpf(sum0);

    // ---- iteration 1: knock out mi0, repeat ----
    float m1 = -INFINITY;
    int mi1 = 0;
#pragma unroll
    for (int j = 0; j < NEXP; ++j) {
        if (j == mi0) continue;
        if (x[j] > m1) { m1 = x[j]; mi1 = j; }
    }
    float sum1 = 0.f;
#pragma unroll
    for (int j = 0; j < NEXP; ++j) {
        if (j == mi0) continue;
        float den = fmaxf(fabsf(x[j]), m1);
        bool masked = (m1 - x[j]) > 0.02f * den;
        sum1 += masked ? 0.f : __expf(x[j] - m1);
    }
    float v1 = __builtin_amdgcn_rcpf(sum1);

    // ---- outputs: [N,2] indices (as float), then [N,2] values ----
    float2* oidx = reinterpret_cast<float2*>(out);
    float2* oval = reinterpret_cast<float2*>(out) + n_tok;
    oidx[t] = make_float2((float)mi0, (float)mi1);
    oval[t] = make_float2(v0, v1);
}

extern "C" void kernel_launch(void* const* d_in, const int* in_sizes, int n_in,
                              void* d_out, int out_size, void* d_ws, size_t ws_size,
                              hipStream_t stream) {
    const float* logits = (const float*)d_in[0];
    float* out = (float*)d_out;
    int n_tok = in_sizes[0] / NEXP;
    int block = 256;
    int grid = (n_tok + block - 1) / block;
    sparsemixer_kernel<<<grid, block, 0, stream>>>(logits, out, n_tok);
}